// Round 5
// baseline (73.519 us; speedup 1.0000x reference)
//
#include <hip/hip_runtime.h>
#include <hip/hip_bf16.h>
#include <math.h>

#define TOK 16384
#define HDIM 2048
#define NE 64
#define NB 4
#define KTOP 8
#define KC 64
#define NC (HDIM / KC)   // 32 chunks

typedef __attribute__((ext_vector_type(8))) __bf16 bf16x8;
typedef __attribute__((ext_vector_type(4))) float f32x4;
typedef unsigned int uint;

__device__ __forceinline__ uint asu(float f) { union { float f; uint u; } c; c.f = f; return c.u; }
__device__ __forceinline__ float asf(uint u) { union { uint u; float f; } c; c.u = u; return c.f; }
__device__ __forceinline__ bf16x8 u2b(uint4 u) { union { uint4 u; bf16x8 b; } c; c.u = u; return c.b; }

// Exact 3-way bf16 split: h+m+l == x bitwise (8 mantissa bits per plane).
__device__ __forceinline__ void split3(float v, uint& h, uint& m, uint& l) {
  uint u = asu(v);
  h = u & 0xffff0000u;
  float d = v - asf(h);
  m = asu(d) & 0xffff0000u;
  float d2 = d - asf(m);
  l = asu(d2);
}

// 8 floats (one fragment k-slot) -> 3 bf16x8 planes, in-register.
__device__ __forceinline__ void split8(float4 a, float4 b,
                                       bf16x8& h8, bf16x8& m8, bf16x8& l8) {
  union { uint4 u; bf16x8 v; } H, M, L;
  uint h0, m0, l0, h1, m1, l1;
  split3(a.x, h0, m0, l0); split3(a.y, h1, m1, l1);
  H.u.x = (h0 >> 16) | (h1 & 0xffff0000u);
  M.u.x = (m0 >> 16) | (m1 & 0xffff0000u);
  L.u.x = (l0 >> 16) | (l1 & 0xffff0000u);
  split3(a.z, h0, m0, l0); split3(a.w, h1, m1, l1);
  H.u.y = (h0 >> 16) | (h1 & 0xffff0000u);
  M.u.y = (m0 >> 16) | (m1 & 0xffff0000u);
  L.u.y = (l0 >> 16) | (l1 & 0xffff0000u);
  split3(b.x, h0, m0, l0); split3(b.y, h1, m1, l1);
  H.u.z = (h0 >> 16) | (h1 & 0xffff0000u);
  M.u.z = (m0 >> 16) | (m1 & 0xffff0000u);
  L.u.z = (l0 >> 16) | (l1 & 0xffff0000u);
  split3(b.z, h0, m0, l0); split3(b.w, h1, m1, l1);
  H.u.w = (h0 >> 16) | (h1 & 0xffff0000u);
  M.u.w = (m0 >> 16) | (m1 & 0xffff0000u);
  L.u.w = (l0 >> 16) | (l1 & 0xffff0000u);
  h8 = H.v; m8 = M.v; l8 = L.v;
}

// ---------------------------------------------------------------------------
// wsplit: pack W into B-fragment order, 3 exact bf16 planes, and zero ce/ssum.
// byte addr = c*24576 + ks*12288 + half*6144 + f2*3072 + plane*1024 + lane*16
// Fragment (c,ks,half,f2,plane,lane): e = half*32+f2*16+(lane&15),
//                                     k = c*64+ks*32+(lane>>4)*8
// ---------------------------------------------------------------------------
__global__ __launch_bounds__(256) void wsplit(const float* __restrict__ w,
                                              char* __restrict__ wpk,
                                              float* __restrict__ stats) {
  if (blockIdx.x == 0 && threadIdx.x < 128) {   // zero ce+ssum (512 floats)
    *(float4*)(stats + threadIdx.x * 4) = make_float4(0.f, 0.f, 0.f, 0.f);
  }
  int t = blockIdx.x * 256 + threadIdx.x;    // 16384 threads
  int lane = t & 63;
  int f2 = (t >> 6) & 1, half = (t >> 7) & 1, ks = (t >> 8) & 1, c = t >> 9;
  int e = half * 32 + f2 * 16 + (lane & 15);
  int k = c * 64 + ks * 32 + ((lane >> 4) << 3);
  const float* p = w + (size_t)e * HDIM + k;
  bf16x8 h8, m8, l8;
  split8(*(const float4*)p, *(const float4*)(p + 4), h8, m8, l8);
  union { bf16x8 v; uint4 u; } H, M, L;
  H.v = h8; M.v = m8; L.v = l8;
  size_t base = (size_t)c * 24576 + (size_t)ks * 12288 + (size_t)half * 6144
              + (size_t)f2 * 3072 + (size_t)lane * 16;
  *(uint4*)(wpk + base) = H.u;
  *(uint4*)(wpk + base + 1024) = M.u;
  *(uint4*)(wpk + base + 2048) = L.u;
}

// ---------------------------------------------------------------------------
// Fused gate, barrier-free K-loop. 256 blocks x 512 thr (8 waves).
// Wave = 16 tokens x 32 experts (2 C-frags). Both MFMA operands in registers:
//   X: global->reg, A-fragment-native layout, depth-2 prefetch, split3 in-reg.
//   W: global->reg from fragment-linear wpk (L2-resident), depth-1 prefetch.
// No LDS in the K-loop; one raw s_barrier/chunk only for L1 W-sharing
// convergence (no memory drain attached).
// ---------------------------------------------------------------------------
__global__ __launch_bounds__(512, 2) void gate_fused(const float* __restrict__ x,
                                                     const char* __restrict__ wpk,
                                                     float* __restrict__ out,
                                                     float* __restrict__ ce,
                                                     float* __restrict__ ssum) {
  __shared__ float sc[NE][65];
  __shared__ float hist[NE];

  const int tid = threadIdx.x;
  const int bid = blockIdx.x;
  const int t0 = bid * 64;
  const int b = bid >> 6;
  const int lane = tid & 63;
  const int wid = tid >> 6;
  const int half = wid & 1;                   // expert half
  const int tg = (wid >> 1) << 4;             // token group base

  if (tid < NE) hist[tid] = 0.f;

  // per-lane X base: row = t0+tg+(lane&15), k-slot offset (lane>>4)*8
  const float* xrow = x + (size_t)(t0 + tg + (lane & 15)) * HDIM + ((lane >> 4) << 3);
  const char* wbase = wpk + half * 6144 + lane * 16;

  f32x4 acc[2] = {{0.f, 0.f, 0.f, 0.f}, {0.f, 0.f, 0.f, 0.f}};
  uint4 WA[12], WB[12];
  float4 xa0, xa1, xa2, xa3, xb0, xb1, xb2, xb3;

#define LOADW(W, c)                                                           \
  {                                                                           \
    const char* wp_ = wbase + (size_t)(c) * 24576;                            \
    _Pragma("unroll")                                                         \
    for (int ks = 0; ks < 2; ++ks)                                            \
      _Pragma("unroll")                                                       \
      for (int f2 = 0; f2 < 2; ++f2)                                          \
        _Pragma("unroll")                                                     \
        for (int pl = 0; pl < 3; ++pl)                                        \
          W[ks * 6 + f2 * 3 + pl] =                                           \
              *(const uint4*)(wp_ + ks * 12288 + f2 * 3072 + pl * 1024);      \
  }

#define LOADX(V0, V1, V2, V3, c)                                              \
  {                                                                           \
    const float* xp_ = xrow + (size_t)(c) * 64;                               \
    V0 = *(const float4*)(xp_);                                               \
    V1 = *(const float4*)(xp_ + 4);                                           \
    V2 = *(const float4*)(xp_ + 32);                                          \
    V3 = *(const float4*)(xp_ + 36);                                          \
  }

#define BODY(W, WN, X0, X1, X2, X3, c)                                        \
  {                                                                           \
    if ((c) + 1 < NC) LOADW(WN, (c) + 1);                                     \
    bf16x8 ah0, am0, al0, ah1, am1, al1;                                      \
    split8(X0, X1, ah0, am0, al0);                                            \
    split8(X2, X3, ah1, am1, al1);                                            \
    if ((c) + 2 < NC) LOADX(X0, X1, X2, X3, (c) + 2);                         \
    _Pragma("unroll")                                                         \
    for (int f2 = 0; f2 < 2; ++f2) {                                          \
      bf16x8 bh0 = u2b(W[f2 * 3 + 0]);                                        \
      bf16x8 bm0 = u2b(W[f2 * 3 + 1]);                                        \
      bf16x8 bl0 = u2b(W[f2 * 3 + 2]);                                        \
      acc[f2] = __builtin_amdgcn_mfma_f32_16x16x32_bf16(ah0, bh0, acc[f2], 0, 0, 0); \
      acc[f2] = __builtin_amdgcn_mfma_f32_16x16x32_bf16(ah0, bm0, acc[f2], 0, 0, 0); \
      acc[f2] = __builtin_amdgcn_mfma_f32_16x16x32_bf16(am0, bh0, acc[f2], 0, 0, 0); \
      acc[f2] = __builtin_amdgcn_mfma_f32_16x16x32_bf16(ah0, bl0, acc[f2], 0, 0, 0); \
      acc[f2] = __builtin_amdgcn_mfma_f32_16x16x32_bf16(al0, bh0, acc[f2], 0, 0, 0); \
      acc[f2] = __builtin_amdgcn_mfma_f32_16x16x32_bf16(am0, bm0, acc[f2], 0, 0, 0); \
      bf16x8 bh1 = u2b(W[6 + f2 * 3 + 0]);                                    \
      bf16x8 bm1 = u2b(W[6 + f2 * 3 + 1]);                                    \
      bf16x8 bl1 = u2b(W[6 + f2 * 3 + 2]);                                    \
      acc[f2] = __builtin_amdgcn_mfma_f32_16x16x32_bf16(ah1, bh1, acc[f2], 0, 0, 0); \
      acc[f2] = __builtin_amdgcn_mfma_f32_16x16x32_bf16(ah1, bm1, acc[f2], 0, 0, 0); \
      acc[f2] = __builtin_amdgcn_mfma_f32_16x16x32_bf16(am1, bh1, acc[f2], 0, 0, 0); \
      acc[f2] = __builtin_amdgcn_mfma_f32_16x16x32_bf16(ah1, bl1, acc[f2], 0, 0, 0); \
      acc[f2] = __builtin_amdgcn_mfma_f32_16x16x32_bf16(al1, bh1, acc[f2], 0, 0, 0); \
      acc[f2] = __builtin_amdgcn_mfma_f32_16x16x32_bf16(am1, bm1, acc[f2], 0, 0, 0); \
    }                                                                         \
    __builtin_amdgcn_s_barrier();   /* convergence only; no drain */          \
  }

  LOADW(WA, 0);
  LOADX(xa0, xa1, xa2, xa3, 0);
  LOADX(xb0, xb1, xb2, xb3, 1);

#pragma unroll 1
  for (int cc = 0; cc < NC; cc += 2) {
    BODY(WA, WB, xa0, xa1, xa2, xa3, cc);
    BODY(WB, WA, xb0, xb1, xb2, xb3, cc + 1);
  }
#undef BODY
#undef LOADW
#undef LOADX

  // C frags -> sc[expert][token]. C layout: col(=expert)=lane&15,
  // row(=token)=(lane>>4)*4+reg  [m89-verified]
#pragma unroll
  for (int f2 = 0; f2 < 2; ++f2) {
    int e = half * 32 + f2 * 16 + (lane & 15);
    int tk = tg + ((lane >> 4) << 2);
    sc[e][tk + 0] = acc[f2][0];
    sc[e][tk + 1] = acc[f2][1];
    sc[e][tk + 2] = acc[f2][2];
    sc[e][tk + 3] = acc[f2][3];
  }
  __syncthreads();

  // softmax + top-8: 8 lanes per token, 8 experts per lane
  const int t = tid >> 3;
  const int j = tid & 7;
  float p[8];
#pragma unroll
  for (int i = 0; i < 8; ++i) p[i] = sc[j * 8 + i][t];

  float m = p[0];
#pragma unroll
  for (int i = 1; i < 8; ++i) m = fmaxf(m, p[i]);
  m = fmaxf(m, __shfl_xor(m, 1, 8));
  m = fmaxf(m, __shfl_xor(m, 2, 8));
  m = fmaxf(m, __shfl_xor(m, 4, 8));
  float s = 0.f;
#pragma unroll
  for (int i = 0; i < 8; ++i) { p[i] = __expf(p[i] - m); s += p[i]; }
  s += __shfl_xor(s, 1, 8);
  s += __shfl_xor(s, 2, 8);
  s += __shfl_xor(s, 4, 8);
  float inv = 1.f / s;
#pragma unroll
  for (int i = 0; i < 8; ++i) { p[i] *= inv; sc[j * 8 + i][t] = p[i]; }

  // top-8: strict-> scan (lowest idx on tie), 8-lane (val,idx) reduce
  unsigned used = 0;
  float wsum = 0.f;
  float wv[KTOP];
  int wi_[KTOP];
#pragma unroll
  for (int sel = 0; sel < KTOP; ++sel) {
    float bv = -1.f;
    int bi = 0;
#pragma unroll
    for (int i = 0; i < 8; ++i) {
      bool ok = !((used >> i) & 1u);
      if (ok && p[i] > bv) { bv = p[i]; bi = i; }
    }
    int ge = j * 8 + bi;
#pragma unroll
    for (int mk = 1; mk < 8; mk <<= 1) {
      float ov = __shfl_xor(bv, mk, 8);
      int og = __shfl_xor(ge, mk, 8);
      if (ov > bv || (ov == bv && og < ge)) { bv = ov; ge = og; }
    }
    if ((ge >> 3) == j) used |= 1u << (ge & 7);
    wv[sel] = bv;
    wi_[sel] = ge;
    wsum += bv;
  }
  if (j == 0) {
    float winv = 1.f / (wsum + 1e-20f);
#pragma unroll
    for (int sel = 0; sel < KTOP; ++sel) {
      out[(size_t)(t0 + t) * KTOP + sel] = (float)wi_[sel];
      out[(size_t)TOK * KTOP + (size_t)(t0 + t) * KTOP + sel] = wv[sel] * winv;
      atomicAdd(&hist[wi_[sel]], 1.f);
    }
  }
  __syncthreads();

  if (tid < NE) {
    float ssl = 0.f;
#pragma unroll
    for (int tt = 0; tt < 64; ++tt) ssl += sc[tid][tt];
    atomicAdd(&ssum[b * NE + tid], ssl);
    atomicAdd(&ce[b * NE + tid], hist[tid]);
  }
}

// ---------------------------------------------------------------------------
// Finalize expert_loads + aux_loss
// ---------------------------------------------------------------------------
__global__ __launch_bounds__(64) void gate_final(const float* __restrict__ ce,
                                                 const float* __restrict__ ssum,
                                                 float* __restrict__ out) {
  const int e = threadIdx.x;
  float loads = 0.f, aux = 0.f;
#pragma unroll
  for (int b = 0; b < NB; ++b) {
    float c = ce[b * 64 + e];
    loads += c;
    aux += (c / 512.0f) * (ssum[b * 64 + e] / 4096.0f);  // (S*K/E)=512, S=4096
  }
  out[(size_t)2 * TOK * KTOP + 1 + e] = loads;
#pragma unroll
  for (int off = 32; off > 0; off >>= 1) aux += __shfl_down(aux, off);
  if (e == 0) out[(size_t)2 * TOK * KTOP] = aux * (0.1f / 4.0f);  // ALPHA/B
}

extern "C" void kernel_launch(void* const* d_in, const int* in_sizes, int n_in,
                              void* d_out, int out_size, void* d_ws, size_t ws_size,
                              hipStream_t stream) {
  const float* x = (const float*)d_in[0];
  const float* w = (const float*)d_in[1];
  float* out = (float*)d_out;

  char* wpk = (char*)d_ws;                         // 32 chunks x 24 KB = 768 KB
  float* ce = (float*)(wpk + (size_t)NC * 24576);  // [NB][NE]
  float* ssum = ce + NB * NE;                      // [NB][NE]

  wsplit<<<dim3(64), dim3(256), 0, stream>>>(w, wpk, ce);
  gate_fused<<<dim3(TOK / 64), dim3(512), 0, stream>>>(x, wpk, out, ce, ssum);
  gate_final<<<dim3(1), dim3(64), 0, stream>>>(ce, ssum, out);
}

// Round 6
// 66.282 us; speedup vs baseline: 1.1092x; 1.1092x over previous
//
#include <hip/hip_runtime.h>
#include <hip/hip_bf16.h>
#include <math.h>

#define TOK 16384
#define HDIM 2048
#define NE 64
#define NB 4
#define KTOP 8
#define KC 64
#define NC (HDIM / KC)   // 32 chunks
#define BT 32            // tokens per block

typedef __attribute__((ext_vector_type(8))) __bf16 bf16x8;
typedef __attribute__((ext_vector_type(4))) float f32x4;
typedef unsigned int uint;

__device__ __forceinline__ uint asu(float f) { union { float f; uint u; } c; c.f = f; return c.u; }
__device__ __forceinline__ float asf(uint u) { union { uint u; float f; } c; c.u = u; return c.f; }

// Exact 3-way bf16 split: h+m+l == x bitwise (8 mantissa bits per plane).
__device__ __forceinline__ void split3(float v, uint& h, uint& m, uint& l) {
  uint u = asu(v);
  h = u & 0xffff0000u;
  float d = v - asf(h);
  m = asu(d) & 0xffff0000u;
  float d2 = d - asf(m);
  l = asu(d2);
}

// 8 floats (one fragment k-slot) -> 3 bf16x8 planes, in-register.
__device__ __forceinline__ void split8(float4 a, float4 b,
                                       bf16x8& h8, bf16x8& m8, bf16x8& l8) {
  union { uint4 u; bf16x8 v; } H, M, L;
  uint h0, m0, l0, h1, m1, l1;
  split3(a.x, h0, m0, l0); split3(a.y, h1, m1, l1);
  H.u.x = (h0 >> 16) | (h1 & 0xffff0000u);
  M.u.x = (m0 >> 16) | (m1 & 0xffff0000u);
  L.u.x = (l0 >> 16) | (l1 & 0xffff0000u);
  split3(a.z, h0, m0, l0); split3(a.w, h1, m1, l1);
  H.u.y = (h0 >> 16) | (h1 & 0xffff0000u);
  M.u.y = (m0 >> 16) | (m1 & 0xffff0000u);
  L.u.y = (l0 >> 16) | (l1 & 0xffff0000u);
  split3(b.x, h0, m0, l0); split3(b.y, h1, m1, l1);
  H.u.z = (h0 >> 16) | (h1 & 0xffff0000u);
  M.u.z = (m0 >> 16) | (m1 & 0xffff0000u);
  L.u.z = (l0 >> 16) | (l1 & 0xffff0000u);
  split3(b.z, h0, m0, l0); split3(b.w, h1, m1, l1);
  H.u.w = (h0 >> 16) | (h1 & 0xffff0000u);
  M.u.w = (m0 >> 16) | (m1 & 0xffff0000u);
  L.u.w = (l0 >> 16) | (l1 & 0xffff0000u);
  h8 = H.v; m8 = M.v; l8 = L.v;
}

__device__ __forceinline__ void gl_lds16(const void* g, void* l) {
  __builtin_amdgcn_global_load_lds(
      (const __attribute__((address_space(1))) void*)g,
      (__attribute__((address_space(3))) void*)l, 16, 0, 0);
}

// ---------------------------------------------------------------------------
// wsplit: pack W into B-fragment order, 3 exact bf16 planes; zero ce/ssum.
// byte addr = c*24576 + ks*12288 + half*6144 + f2*3072 + plane*1024 + lane*16
// Fragment (c,ks,half,f2,plane,lane): e = half*32+f2*16+(lane&15),
//                                     k = c*64+ks*32+(lane>>4)*8
// ---------------------------------------------------------------------------
__global__ __launch_bounds__(256) void wsplit(const float* __restrict__ w,
                                              char* __restrict__ wpk,
                                              float* __restrict__ stats) {
  if (blockIdx.x == 0 && threadIdx.x < 128) {   // zero ce+ssum (512 floats)
    *(float4*)(stats + threadIdx.x * 4) = make_float4(0.f, 0.f, 0.f, 0.f);
  }
  int t = blockIdx.x * 256 + threadIdx.x;    // 16384 threads
  int lane = t & 63;
  int f2 = (t >> 6) & 1, half = (t >> 7) & 1, ks = (t >> 8) & 1, c = t >> 9;
  int e = half * 32 + f2 * 16 + (lane & 15);
  int k = c * 64 + ks * 32 + ((lane >> 4) << 3);
  const float* p = w + (size_t)e * HDIM + k;
  bf16x8 h8, m8, l8;
  split8(*(const float4*)p, *(const float4*)(p + 4), h8, m8, l8);
  union { bf16x8 v; uint4 u; } H, M, L;
  H.v = h8; M.v = m8; L.v = l8;
  size_t base = (size_t)c * 24576 + (size_t)ks * 12288 + (size_t)half * 6144
              + (size_t)f2 * 3072 + (size_t)lane * 16;
  *(uint4*)(wpk + base) = H.u;
  *(uint4*)(wpk + base + 1024) = M.u;
  *(uint4*)(wpk + base + 2048) = L.u;
}

// ---------------------------------------------------------------------------
// Fused gate. 512 blocks x 256 thr (4 waves) -> 2 blocks/CU so one block's
// barrier/vmcnt stall is covered by the other block's compute (round-5 lesson:
// plain-load W prefetch gets sunk by the compiler; gl_lds cannot be).
// Wave = 16 tokens x 32 experts (2 C-frags).
//   X: global->reg (A-fragment native layout), depth-2 prefetch, split3 in-reg
//      (split3 is a real use -> compiler keeps the prefetch distance).
//   W: global_load_lds (16B) into 2x24 KB LDS dbuf, fragment-linear layout.
// One raw s_barrier per chunk; counted vmcnt(4) keeps X in flight across it.
// ---------------------------------------------------------------------------
__global__ __launch_bounds__(256, 2) void gate_fused(const float* __restrict__ x,
                                                     const char* __restrict__ wpk,
                                                     float* __restrict__ out,
                                                     float* __restrict__ ce,
                                                     float* __restrict__ ssum) {
  __shared__ __align__(16) char lds[49152];   // W dbuf: 2 x 24 KB
  __shared__ float hist[NE];

  const int tid = threadIdx.x;
  const int bid = blockIdx.x;
  const int t0 = bid * BT;
  const int b = bid >> 7;                     // 128 blocks per batch row
  const int lane = tid & 63;
  const int wid = tid >> 6;                   // 0..3
  const int half = wid & 1;                   // expert half
  const int tg = (wid >> 1) << 4;             // token group base: 0 or 16

  if (tid < NE) hist[tid] = 0.f;

  char* buf0 = lds;
  char* buf1 = lds + 24576;

  // per-lane X base: row = t0+tg+(lane&15), k-slot offset (lane>>4)*8
  const float* xrow = x + (size_t)(t0 + tg + (lane & 15)) * HDIM + ((lane >> 4) << 3);

  f32x4 acc[2] = {{0.f, 0.f, 0.f, 0.f}, {0.f, 0.f, 0.f, 0.f}};

  // ---- prologue: W(0) -> buf0 (6 gl_lds: slots i*4+wid); X(0), X(1) -> regs
  {
    const char* wsp0 = wpk + (size_t)lane * 16;
#pragma unroll
    for (int i = 0; i < 6; ++i)
      gl_lds16(wsp0 + (i * 4 + wid) * 1024, buf0 + (i * 4 + wid) * 1024);
  }
  float4 xa0 = *(const float4*)(xrow);
  float4 xa1 = *(const float4*)(xrow + 4);
  float4 xa2 = *(const float4*)(xrow + 32);
  float4 xa3 = *(const float4*)(xrow + 36);
  float4 xb0 = *(const float4*)(xrow + 64);
  float4 xb1 = *(const float4*)(xrow + 68);
  float4 xb2 = *(const float4*)(xrow + 96);
  float4 xb3 = *(const float4*)(xrow + 100);
  asm volatile("s_waitcnt vmcnt(8)" ::: "memory");  // W(0) done; X(0,1) in flight
  __builtin_amdgcn_s_barrier();
  asm volatile("" ::: "memory");

#define CHUNK(c, X0, X1, X2, X3, BR, BW)                                        \
  {                                                                             \
    if ((c) + 1 < NC) {   /* 1: stage W(c+1) -> BW (async, unsinkable) */       \
      const char* wsp = wpk + (size_t)((c) + 1) * 24576 + (size_t)lane * 16;    \
      _Pragma("unroll")                                                         \
      for (int i = 0; i < 6; ++i)                                               \
        gl_lds16(wsp + (i * 4 + wid) * 1024, BW + (i * 4 + wid) * 1024);        \
    }                                                                           \
    bf16x8 ah0, am0, al0, ah1, am1, al1;     /* 2: split X(c) */                \
    split8(X0, X1, ah0, am0, al0);                                              \
    split8(X2, X3, ah1, am1, al1);                                              \
    if ((c) + 2 < NC) {   /* 3: issue X(c+2) */                                 \
      const float* xp = xrow + (size_t)((c) + 2) * 64;                          \
      X0 = *(const float4*)(xp);                                                \
      X1 = *(const float4*)(xp + 4);                                            \
      X2 = *(const float4*)(xp + 32);                                           \
      X3 = *(const float4*)(xp + 36);                                           \
    }                                                                           \
    _Pragma("unroll")     /* 4: MFMA on BR = W(c) */                            \
    for (int f2 = 0; f2 < 2; ++f2) {                                            \
      const char* bb0 = BR + half * 6144 + f2 * 3072 + lane * 16;               \
      bf16x8 bh = *(const bf16x8*)(bb0);                                        \
      bf16x8 bm = *(const bf16x8*)(bb0 + 1024);                                 \
      bf16x8 bl = *(const bf16x8*)(bb0 + 2048);                                 \
      acc[f2] = __builtin_amdgcn_mfma_f32_16x16x32_bf16(ah0, bh, acc[f2], 0, 0, 0); \
      acc[f2] = __builtin_amdgcn_mfma_f32_16x16x32_bf16(ah0, bm, acc[f2], 0, 0, 0); \
      acc[f2] = __builtin_amdgcn_mfma_f32_16x16x32_bf16(am0, bh, acc[f2], 0, 0, 0); \
      acc[f2] = __builtin_amdgcn_mfma_f32_16x16x32_bf16(ah0, bl, acc[f2], 0, 0, 0); \
      acc[f2] = __builtin_amdgcn_mfma_f32_16x16x32_bf16(al0, bh, acc[f2], 0, 0, 0); \
      acc[f2] = __builtin_amdgcn_mfma_f32_16x16x32_bf16(am0, bm, acc[f2], 0, 0, 0); \
      const char* bb1 = BR + 12288 + half * 6144 + f2 * 3072 + lane * 16;       \
      bf16x8 kh = *(const bf16x8*)(bb1);                                        \
      bf16x8 km = *(const bf16x8*)(bb1 + 1024);                                 \
      bf16x8 kl = *(const bf16x8*)(bb1 + 2048);                                 \
      acc[f2] = __builtin_amdgcn_mfma_f32_16x16x32_bf16(ah1, kh, acc[f2], 0, 0, 0); \
      acc[f2] = __builtin_amdgcn_mfma_f32_16x16x32_bf16(ah1, km, acc[f2], 0, 0, 0); \
      acc[f2] = __builtin_amdgcn_mfma_f32_16x16x32_bf16(am1, kh, acc[f2], 0, 0, 0); \
      acc[f2] = __builtin_amdgcn_mfma_f32_16x16x32_bf16(ah1, kl, acc[f2], 0, 0, 0); \
      acc[f2] = __builtin_amdgcn_mfma_f32_16x16x32_bf16(al1, kh, acc[f2], 0, 0, 0); \
      acc[f2] = __builtin_amdgcn_mfma_f32_16x16x32_bf16(am1, km, acc[f2], 0, 0, 0); \
    }                                                                           \
    /* 5/6: W(c+1) landed for THIS wave, then barrier -> visible to all */      \
    if ((c) < NC - 2) { asm volatile("s_waitcnt vmcnt(4)" ::: "memory"); }      \
    else              { asm volatile("s_waitcnt vmcnt(0)" ::: "memory"); }      \
    __builtin_amdgcn_s_barrier();                                               \
    asm volatile("" ::: "memory");                                              \
  }

#pragma unroll 1
  for (int cc = 0; cc < NC; cc += 2) {
    CHUNK(cc,     xa0, xa1, xa2, xa3, buf0, buf1);
    CHUNK(cc + 1, xb0, xb1, xb2, xb3, buf1, buf0);
  }
#undef CHUNK

  // scores overlay buf0 (last chunk read buf1; final barrier precedes writes).
  // C layout: col(=expert)=lane&15, row(=token)=(lane>>4)*4+reg  [m89]
  float (*sc)[33] = (float(*)[33])lds;
#pragma unroll
  for (int f2 = 0; f2 < 2; ++f2) {
    int e = half * 32 + f2 * 16 + (lane & 15);
    int tk = tg + ((lane >> 4) << 2);
    sc[e][tk + 0] = acc[f2][0];
    sc[e][tk + 1] = acc[f2][1];
    sc[e][tk + 2] = acc[f2][2];
    sc[e][tk + 3] = acc[f2][3];
  }
  __syncthreads();

  // softmax + top-8: 8 lanes per token (t = 0..31), 8 experts per lane
  const int t = tid >> 3;
  const int j = tid & 7;
  float p[8];
#pragma unroll
  for (int i = 0; i < 8; ++i) p[i] = sc[j * 8 + i][t];

  float m = p[0];
#pragma unroll
  for (int i = 1; i < 8; ++i) m = fmaxf(m, p[i]);
  m = fmaxf(m, __shfl_xor(m, 1, 8));
  m = fmaxf(m, __shfl_xor(m, 2, 8));
  m = fmaxf(m, __shfl_xor(m, 4, 8));
  float s = 0.f;
#pragma unroll
  for (int i = 0; i < 8; ++i) { p[i] = __expf(p[i] - m); s += p[i]; }
  s += __shfl_xor(s, 1, 8);
  s += __shfl_xor(s, 2, 8);
  s += __shfl_xor(s, 4, 8);
  float inv = 1.f / s;
#pragma unroll
  for (int i = 0; i < 8; ++i) { p[i] *= inv; sc[j * 8 + i][t] = p[i]; }

  // top-8: strict-> scan (lowest idx on tie), 8-lane (val,idx) reduce
  unsigned used = 0;
  float wsum = 0.f;
  float wv[KTOP];
  int wi_[KTOP];
#pragma unroll
  for (int sel = 0; sel < KTOP; ++sel) {
    float bv = -1.f;
    int bi = 0;
#pragma unroll
    for (int i = 0; i < 8; ++i) {
      bool ok = !((used >> i) & 1u);
      if (ok && p[i] > bv) { bv = p[i]; bi = i; }
    }
    int ge = j * 8 + bi;
#pragma unroll
    for (int mk = 1; mk < 8; mk <<= 1) {
      float ov = __shfl_xor(bv, mk, 8);
      int og = __shfl_xor(ge, mk, 8);
      if (ov > bv || (ov == bv && og < ge)) { bv = ov; ge = og; }
    }
    if ((ge >> 3) == j) used |= 1u << (ge & 7);
    wv[sel] = bv;
    wi_[sel] = ge;
    wsum += bv;
  }
  if (j == 0) {
    float winv = 1.f / (wsum + 1e-20f);
#pragma unroll
    for (int sel = 0; sel < KTOP; ++sel) {
      out[(size_t)(t0 + t) * KTOP + sel] = (float)wi_[sel];
      out[(size_t)TOK * KTOP + (size_t)(t0 + t) * KTOP + sel] = wv[sel] * winv;
      atomicAdd(&hist[wi_[sel]], 1.f);
    }
  }
  __syncthreads();

  if (tid < NE) {
    float ssl = 0.f;
#pragma unroll
    for (int tt = 0; tt < BT; ++tt) ssl += sc[tid][tt];
    atomicAdd(&ssum[b * NE + tid], ssl);
    atomicAdd(&ce[b * NE + tid], hist[tid]);
  }
}

// ---------------------------------------------------------------------------
// Finalize expert_loads + aux_loss
// ---------------------------------------------------------------------------
__global__ __launch_bounds__(64) void gate_final(const float* __restrict__ ce,
                                                 const float* __restrict__ ssum,
                                                 float* __restrict__ out) {
  const int e = threadIdx.x;
  float loads = 0.f, aux = 0.f;
#pragma unroll
  for (int b = 0; b < NB; ++b) {
    float c = ce[b * 64 + e];
    loads += c;
    aux += (c / 512.0f) * (ssum[b * 64 + e] / 4096.0f);  // (S*K/E)=512, S=4096
  }
  out[(size_t)2 * TOK * KTOP + 1 + e] = loads;
#pragma unroll
  for (int off = 32; off > 0; off >>= 1) aux += __shfl_down(aux, off);
  if (e == 0) out[(size_t)2 * TOK * KTOP] = aux * (0.1f / 4.0f);  // ALPHA/B
}

extern "C" void kernel_launch(void* const* d_in, const int* in_sizes, int n_in,
                              void* d_out, int out_size, void* d_ws, size_t ws_size,
                              hipStream_t stream) {
  const float* x = (const float*)d_in[0];
  const float* w = (const float*)d_in[1];
  float* out = (float*)d_out;

  char* wpk = (char*)d_ws;                         // 32 chunks x 24 KB = 768 KB
  float* ce = (float*)(wpk + (size_t)NC * 24576);  // [NB][NE]
  float* ssum = ce + NB * NE;                      // [NB][NE]

  wsplit<<<dim3(64), dim3(256), 0, stream>>>(w, wpk, ce);
  gate_fused<<<dim3(TOK / BT), dim3(256), 0, stream>>>(x, wpk, out, ce, ssum);
  gate_final<<<dim3(1), dim3(64), 0, stream>>>(ce, ssum, out);
}

// Round 8
// 63.271 us; speedup vs baseline: 1.1620x; 1.0476x over previous
//
#include <hip/hip_runtime.h>
#include <hip/hip_bf16.h>
#include <math.h>

#define TOK 16384
#define HDIM 2048
#define NE 64
#define NB 4
#define KTOP 8
#define KC 64
#define NC (HDIM / KC)   // 32 chunks
#define BT 32            // tokens per block

typedef __attribute__((ext_vector_type(8))) __bf16 bf16x8;
typedef __attribute__((ext_vector_type(4))) float f32x4;
typedef unsigned int uint;

__device__ __forceinline__ uint asu(float f) { union { float f; uint u; } c; c.f = f; return c.u; }
__device__ __forceinline__ float asf(uint u) { union { uint u; float f; } c; c.u = u; return c.f; }

// Exact 3-way bf16 split: h+m+l == x bitwise (8 mantissa bits per plane).
__device__ __forceinline__ void split3(float v, uint& h, uint& m, uint& l) {
  uint u = asu(v);
  h = u & 0xffff0000u;
  float d = v - asf(h);
  m = asu(d) & 0xffff0000u;
  float d2 = d - asf(m);
  l = asu(d2);
}

// 8 floats (one fragment k-slot) -> 3 bf16x8 planes, in-register.
__device__ __forceinline__ void split8(float4 a, float4 b,
                                       bf16x8& h8, bf16x8& m8, bf16x8& l8) {
  union { uint4 u; bf16x8 v; } H, M, L;
  uint h0, m0, l0, h1, m1, l1;
  split3(a.x, h0, m0, l0); split3(a.y, h1, m1, l1);
  H.u.x = (h0 >> 16) | (h1 & 0xffff0000u);
  M.u.x = (m0 >> 16) | (m1 & 0xffff0000u);
  L.u.x = (l0 >> 16) | (l1 & 0xffff0000u);
  split3(a.z, h0, m0, l0); split3(a.w, h1, m1, l1);
  H.u.y = (h0 >> 16) | (h1 & 0xffff0000u);
  M.u.y = (m0 >> 16) | (m1 & 0xffff0000u);
  L.u.y = (l0 >> 16) | (l1 & 0xffff0000u);
  split3(b.x, h0, m0, l0); split3(b.y, h1, m1, l1);
  H.u.z = (h0 >> 16) | (h1 & 0xffff0000u);
  M.u.z = (m0 >> 16) | (m1 & 0xffff0000u);
  L.u.z = (l0 >> 16) | (l1 & 0xffff0000u);
  split3(b.z, h0, m0, l0); split3(b.w, h1, m1, l1);
  H.u.w = (h0 >> 16) | (h1 & 0xffff0000u);
  M.u.w = (m0 >> 16) | (m1 & 0xffff0000u);
  L.u.w = (l0 >> 16) | (l1 & 0xffff0000u);
  h8 = H.v; m8 = M.v; l8 = L.v;
}

__device__ __forceinline__ void gl_lds16(const void* g, void* l) {
  __builtin_amdgcn_global_load_lds(
      (const __attribute__((address_space(1))) void*)g,
      (__attribute__((address_space(3))) void*)l, 16, 0, 0);
}

// ---------------------------------------------------------------------------
// wsplit: pack W into B-fragment order, 3 exact bf16 planes; zero ce/ssum.
// byte addr = c*24576 + ks*12288 + half*6144 + f2*3072 + plane*1024 + lane*16
// Fragment (c,ks,half,f2,plane,lane): e = half*32+f2*16+(lane&15),
//                                     k = c*64+ks*32+(lane>>4)*8
// ---------------------------------------------------------------------------
__global__ __launch_bounds__(256) void wsplit(const float* __restrict__ w,
                                              char* __restrict__ wpk,
                                              float* __restrict__ stats) {
  if (blockIdx.x == 0 && threadIdx.x < 128) {   // zero ce+ssum (512 floats)
    *(float4*)(stats + threadIdx.x * 4) = make_float4(0.f, 0.f, 0.f, 0.f);
  }
  int t = blockIdx.x * 256 + threadIdx.x;    // 16384 threads
  int lane = t & 63;
  int f2 = (t >> 6) & 1, half = (t >> 7) & 1, ks = (t >> 8) & 1, c = t >> 9;
  int e = half * 32 + f2 * 16 + (lane & 15);
  int k = c * 64 + ks * 32 + ((lane >> 4) << 3);
  const float* p = w + (size_t)e * HDIM + k;
  bf16x8 h8, m8, l8;
  split8(*(const float4*)p, *(const float4*)(p + 4), h8, m8, l8);
  union { bf16x8 v; uint4 u; } H, M, L;
  H.v = h8; M.v = m8; L.v = l8;
  size_t base = (size_t)c * 24576 + (size_t)ks * 12288 + (size_t)half * 6144
              + (size_t)f2 * 3072 + (size_t)lane * 16;
  *(uint4*)(wpk + base) = H.u;
  *(uint4*)(wpk + base + 1024) = M.u;
  *(uint4*)(wpk + base + 2048) = L.u;
}

// ---------------------------------------------------------------------------
// Fused gate. 512 blocks x 256 thr (4 waves), 2 blocks/CU.
// Wave = 16 tokens x 32 experts (2 C-frags).
//   X: global->reg (A-fragment native layout), depth-2 prefetch, split3 in-reg.
//   W: global_load_lds (16B) into a 3 x 24 KB LDS TRIPLE buffer -- W(c+2)
//      issued at chunk c, so every load has a full chunk (~1500 cy) in
//      flight before its wait (round-6 failure mode: W(c+1) had only
//      intra-chunk cover, so each barrier ate the latency shortfall).
// One counted s_waitcnt vmcnt(10) per chunk: the youngest 10 VMEM ops are
// exactly this chunk's {6 gl_lds W(c+2), 4 X(c+2)} (both fenced between the
// volatile-asm waits), so the drain covers W(c+1)+X(c+1) and older.
// ---------------------------------------------------------------------------
__global__ __launch_bounds__(256, 2) void gate_fused(const float* __restrict__ x,
                                                     const char* __restrict__ wpk,
                                                     float* __restrict__ out,
                                                     float* __restrict__ ce,
                                                     float* __restrict__ ssum) {
  __shared__ __align__(16) char lds[3 * 24576];   // W tri-buffer
  __shared__ float hist[NE];

  const int tid = threadIdx.x;
  const int bid = blockIdx.x;
  const int t0 = bid * BT;
  const int b = bid >> 7;                     // 128 blocks per batch row
  const int lane = tid & 63;
  const int wid = tid >> 6;                   // 0..3
  const int half = wid & 1;                   // expert half
  const int tg = (wid >> 1) << 4;             // token group base: 0 or 16

  if (tid < NE) hist[tid] = 0.f;

  char* buf0 = lds;
  char* buf1 = lds + 24576;
  char* buf2 = lds + 49152;

  // per-lane X base: row = t0+tg+(lane&15), k-slot offset (lane>>4)*8
  const float* xrow = x + (size_t)(t0 + tg + (lane & 15)) * HDIM + ((lane >> 4) << 3);

  f32x4 acc[2] = {{0.f, 0.f, 0.f, 0.f}, {0.f, 0.f, 0.f, 0.f}};

  // ---- prologue: W(0)->buf0, X(0); W(1)->buf1, X(1). Order pinned by the
  // empty memory-clobber asm so vmcnt(10) drains exactly {W(0),X(0)}.
  {
    const char* wsp0 = wpk + (size_t)lane * 16;
#pragma unroll
    for (int i = 0; i < 6; ++i)
      gl_lds16(wsp0 + (i * 4 + wid) * 1024, buf0 + (i * 4 + wid) * 1024);
  }
  float4 xa0 = *(const float4*)(xrow);
  float4 xa1 = *(const float4*)(xrow + 4);
  float4 xa2 = *(const float4*)(xrow + 32);
  float4 xa3 = *(const float4*)(xrow + 36);
  asm volatile("" ::: "memory");
  {
    const char* wsp1 = wpk + 24576 + (size_t)lane * 16;
#pragma unroll
    for (int i = 0; i < 6; ++i)
      gl_lds16(wsp1 + (i * 4 + wid) * 1024, buf1 + (i * 4 + wid) * 1024);
  }
  float4 xb0 = *(const float4*)(xrow + 64);
  float4 xb1 = *(const float4*)(xrow + 68);
  float4 xb2 = *(const float4*)(xrow + 96);
  float4 xb3 = *(const float4*)(xrow + 100);
  asm volatile("s_waitcnt vmcnt(10)" ::: "memory");  // W(0)+X(0) done
  __builtin_amdgcn_s_barrier();
  asm volatile("" ::: "memory");

  char* rb = buf0;   // read buffer (W(c))
  char* nb = buf1;   // next (W(c+1), landing)
  char* sb = buf2;   // stage target (W(c+2))

#define CHUNK(c, X0, X1, X2, X3)                                                \
  {                                                                             \
    if ((c) + 2 < NC) {   /* 1: stage W(c+2) -> sb (async, unsinkable) */       \
      const char* wsp = wpk + (size_t)((c) + 2) * 24576 + (size_t)lane * 16;    \
      _Pragma("unroll")                                                         \
      for (int i = 0; i < 6; ++i)                                               \
        gl_lds16(wsp + (i * 4 + wid) * 1024, sb + (i * 4 + wid) * 1024);        \
    }                                                                           \
    bf16x8 ah0, am0, al0, ah1, am1, al1;     /* 2: split X(c) */                \
    split8(X0, X1, ah0, am0, al0);                                              \
    split8(X2, X3, ah1, am1, al1);                                              \
    if ((c) + 2 < NC) {   /* 3: issue X(c+2) */                                 \
      const float* xp = xrow + (size_t)((c) + 2) * 64;                          \
      X0 = *(const float4*)(xp);                                                \
      X1 = *(const float4*)(xp + 4);                                            \
      X2 = *(const float4*)(xp + 32);                                           \
      X3 = *(const float4*)(xp + 36);                                           \
    }                                                                           \
    _Pragma("unroll")     /* 4: MFMA on rb = W(c) */                            \
    for (int f2 = 0; f2 < 2; ++f2) {                                            \
      const char* bb0 = rb + half * 6144 + f2 * 3072 + lane * 16;               \
      bf16x8 bh = *(const bf16x8*)(bb0);                                        \
      bf16x8 bm = *(const bf16x8*)(bb0 + 1024);                                 \
      bf16x8 bl = *(const bf16x8*)(bb0 + 2048);                                 \
      acc[f2] = __builtin_amdgcn_mfma_f32_16x16x32_bf16(ah0, bh, acc[f2], 0, 0, 0); \
      acc[f2] = __builtin_amdgcn_mfma_f32_16x16x32_bf16(ah0, bm, acc[f2], 0, 0, 0); \
      acc[f2] = __builtin_amdgcn_mfma_f32_16x16x32_bf16(am0, bh, acc[f2], 0, 0, 0); \
      acc[f2] = __builtin_amdgcn_mfma_f32_16x16x32_bf16(ah0, bl, acc[f2], 0, 0, 0); \
      acc[f2] = __builtin_amdgcn_mfma_f32_16x16x32_bf16(al0, bh, acc[f2], 0, 0, 0); \
      acc[f2] = __builtin_amdgcn_mfma_f32_16x16x32_bf16(am0, bm, acc[f2], 0, 0, 0); \
      const char* bb1 = rb + 12288 + half * 6144 + f2 * 3072 + lane * 16;       \
      bf16x8 kh = *(const bf16x8*)(bb1);                                        \
      bf16x8 km = *(const bf16x8*)(bb1 + 1024);                                 \
      bf16x8 kl = *(const bf16x8*)(bb1 + 2048);                                 \
      acc[f2] = __builtin_amdgcn_mfma_f32_16x16x32_bf16(ah1, kh, acc[f2], 0, 0, 0); \
      acc[f2] = __builtin_amdgcn_mfma_f32_16x16x32_bf16(ah1, km, acc[f2], 0, 0, 0); \
      acc[f2] = __builtin_amdgcn_mfma_f32_16x16x32_bf16(am1, kh, acc[f2], 0, 0, 0); \
      acc[f2] = __builtin_amdgcn_mfma_f32_16x16x32_bf16(ah1, kl, acc[f2], 0, 0, 0); \
      acc[f2] = __builtin_amdgcn_mfma_f32_16x16x32_bf16(al1, kh, acc[f2], 0, 0, 0); \
      acc[f2] = __builtin_amdgcn_mfma_f32_16x16x32_bf16(am1, km, acc[f2], 0, 0, 0); \
    }                                                                           \
    /* 5: drain W(c+1)+X(c+1) (issued a FULL chunk ago); keep this chunk's */   \
    /*    {W(c+2),X(c+2)} = the 10 youngest in flight. 6: barrier.         */   \
    if ((c) < NC - 2) { asm volatile("s_waitcnt vmcnt(10)" ::: "memory"); }     \
    else              { asm volatile("s_waitcnt vmcnt(0)" ::: "memory"); }      \
    __builtin_amdgcn_s_barrier();                                               \
    asm volatile("" ::: "memory");                                              \
  }

#pragma unroll 1
  for (int cc = 0; cc < NC; cc += 2) {
    CHUNK(cc, xa0, xa1, xa2, xa3);
    { char* t_ = rb; rb = nb; nb = sb; sb = t_; }
    CHUNK(cc + 1, xb0, xb1, xb2, xb3);
    { char* t_ = rb; rb = nb; nb = sb; sb = t_; }
  }
#undef CHUNK

  // scores overlay buf0 region (last chunk read buf1-rotated; all reads of
  // the overlay range finished before the final barrier).
  // C layout: col(=expert)=lane&15, row(=token)=(lane>>4)*4+reg  [m89]
  float (*sc)[BT + 1] = (float(*)[BT + 1])lds;
#pragma unroll
  for (int f2 = 0; f2 < 2; ++f2) {
    int e = half * 32 + f2 * 16 + (lane & 15);
    int tk = tg + ((lane >> 4) << 2);
    sc[e][tk + 0] = acc[f2][0];
    sc[e][tk + 1] = acc[f2][1];
    sc[e][tk + 2] = acc[f2][2];
    sc[e][tk + 3] = acc[f2][3];
  }
  __syncthreads();

  // softmax + top-8: 8 lanes per token (t = 0..31), 8 experts per lane
  const int t = tid >> 3;
  const int j = tid & 7;
  float p[8];
#pragma unroll
  for (int i = 0; i < 8; ++i) p[i] = sc[j * 8 + i][t];

  float m = p[0];
#pragma unroll
  for (int i = 1; i < 8; ++i) m = fmaxf(m, p[i]);
  m = fmaxf(m, __shfl_xor(m, 1, 8));
  m = fmaxf(m, __shfl_xor(m, 2, 8));
  m = fmaxf(m, __shfl_xor(m, 4, 8));
  float s = 0.f;
#pragma unroll
  for (int i = 0; i < 8; ++i) { p[i] = __expf(p[i] - m); s += p[i]; }
  s += __shfl_xor(s, 1, 8);
  s += __shfl_xor(s, 2, 8);
  s += __shfl_xor(s, 4, 8);
  float inv = 1.f / s;
#pragma unroll
  for (int i = 0; i < 8; ++i) { p[i] *= inv; sc[j * 8 + i][t] = p[i]; }

  // top-8: strict-> scan (lowest idx on tie), 8-lane (val,idx) reduce
  unsigned used = 0;
  float wsum = 0.f;
  float wv[KTOP];
  int wi_[KTOP];
#pragma unroll
  for (int sel = 0; sel < KTOP; ++sel) {
    float bv = -1.f;
    int bi = 0;
#pragma unroll
    for (int i = 0; i < 8; ++i) {
      bool ok = !((used >> i) & 1u);
      if (ok && p[i] > bv) { bv = p[i]; bi = i; }
    }
    int ge = j * 8 + bi;
#pragma unroll
    for (int mk = 1; mk < 8; mk <<= 1) {
      float ov = __shfl_xor(bv, mk, 8);
      int og = __shfl_xor(ge, mk, 8);
      if (ov > bv || (ov == bv && og < ge)) { bv = ov; ge = og; }
    }
    if ((ge >> 3) == j) used |= 1u << (ge & 7);
    wv[sel] = bv;
    wi_[sel] = ge;
    wsum += bv;
  }
  if (j == 0) {
    float winv = 1.f / (wsum + 1e-20f);
#pragma unroll
    for (int sel = 0; sel < KTOP; ++sel) {
      out[(size_t)(t0 + t) * KTOP + sel] = (float)wi_[sel];
      out[(size_t)TOK * KTOP + (size_t)(t0 + t) * KTOP + sel] = wv[sel] * winv;
      atomicAdd(&hist[wi_[sel]], 1.f);
    }
  }
  __syncthreads();

  if (tid < NE) {
    float ssl = 0.f;
#pragma unroll
    for (int tt = 0; tt < BT; ++tt) ssl += sc[tid][tt];
    atomicAdd(&ssum[b * NE + tid], ssl);
    atomicAdd(&ce[b * NE + tid], hist[tid]);
  }
}

// ---------------------------------------------------------------------------
// Finalize expert_loads + aux_loss
// ---------------------------------------------------------------------------
__global__ __launch_bounds__(64) void gate_final(const float* __restrict__ ce,
                                                 const float* __restrict__ ssum,
                                                 float* __restrict__ out) {
  const int e = threadIdx.x;
  float loads = 0.f, aux = 0.f;
#pragma unroll
  for (int b = 0; b < NB; ++b) {
    float c = ce[b * 64 + e];
    loads += c;
    aux += (c / 512.0f) * (ssum[b * 64 + e] / 4096.0f);  // (S*K/E)=512, S=4096
  }
  out[(size_t)2 * TOK * KTOP + 1 + e] = loads;
#pragma unroll
  for (int off = 32; off > 0; off >>= 1) aux += __shfl_down(aux, off);
  if (e == 0) out[(size_t)2 * TOK * KTOP] = aux * (0.1f / 4.0f);  // ALPHA/B
}

extern "C" void kernel_launch(void* const* d_in, const int* in_sizes, int n_in,
                              void* d_out, int out_size, void* d_ws, size_t ws_size,
                              hipStream_t stream) {
  const float* x = (const float*)d_in[0];
  const float* w = (const float*)d_in[1];
  float* out = (float*)d_out;

  char* wpk = (char*)d_ws;                         // 32 chunks x 24 KB = 768 KB
  float* ce = (float*)(wpk + (size_t)NC * 24576);  // [NB][NE]
  float* ssum = ce + NB * NE;                      // [NB][NE]

  wsplit<<<dim3(64), dim3(256), 0, stream>>>(w, wpk, ce);
  gate_fused<<<dim3(TOK / BT), dim3(256), 0, stream>>>(x, wpk, out, ce, ssum);
  gate_final<<<dim3(1), dim3(64), 0, stream>>>(ce, ssum, out);
}

// Round 9
// 59.041 us; speedup vs baseline: 1.2452x; 1.0716x over previous
//
#include <hip/hip_runtime.h>
#include <hip/hip_bf16.h>
#include <math.h>

#define TOK 16384
#define HDIM 2048
#define NE 64
#define NB 4
#define KTOP 8
#define KC 64
#define NC (HDIM / KC)   // 32 chunks
#define BT 32            // tokens per block

typedef __attribute__((ext_vector_type(8))) __bf16 bf16x8;
typedef __attribute__((ext_vector_type(4))) float f32x4;
typedef unsigned int uint;

__device__ __forceinline__ uint asu(float f) { union { float f; uint u; } c; c.f = f; return c.u; }
__device__ __forceinline__ float asf(uint u) { union { uint u; float f; } c; c.u = u; return c.f; }

// Exact 3-way bf16 split: h+m+l == x bitwise (8 mantissa bits per plane).
__device__ __forceinline__ void split3(float v, uint& h, uint& m, uint& l) {
  uint u = asu(v);
  h = u & 0xffff0000u;
  float d = v - asf(h);
  m = asu(d) & 0xffff0000u;
  float d2 = d - asf(m);
  l = asu(d2);
}

// 8 floats (one fragment k-slot) -> 3 bf16x8 planes, in-register.
__device__ __forceinline__ void split8(float4 a, float4 b,
                                       bf16x8& h8, bf16x8& m8, bf16x8& l8) {
  union { uint4 u; bf16x8 v; } H, M, L;
  uint h0, m0, l0, h1, m1, l1;
  split3(a.x, h0, m0, l0); split3(a.y, h1, m1, l1);
  H.u.x = (h0 >> 16) | (h1 & 0xffff0000u);
  M.u.x = (m0 >> 16) | (m1 & 0xffff0000u);
  L.u.x = (l0 >> 16) | (l1 & 0xffff0000u);
  split3(a.z, h0, m0, l0); split3(a.w, h1, m1, l1);
  H.u.y = (h0 >> 16) | (h1 & 0xffff0000u);
  M.u.y = (m0 >> 16) | (m1 & 0xffff0000u);
  L.u.y = (l0 >> 16) | (l1 & 0xffff0000u);
  split3(b.x, h0, m0, l0); split3(b.y, h1, m1, l1);
  H.u.z = (h0 >> 16) | (h1 & 0xffff0000u);
  M.u.z = (m0 >> 16) | (m1 & 0xffff0000u);
  L.u.z = (l0 >> 16) | (l1 & 0xffff0000u);
  split3(b.z, h0, m0, l0); split3(b.w, h1, m1, l1);
  H.u.w = (h0 >> 16) | (h1 & 0xffff0000u);
  M.u.w = (m0 >> 16) | (m1 & 0xffff0000u);
  L.u.w = (l0 >> 16) | (l1 & 0xffff0000u);
  h8 = H.v; m8 = M.v; l8 = L.v;
}

__device__ __forceinline__ void gl_lds16(const void* g, void* l) {
  __builtin_amdgcn_global_load_lds(
      (const __attribute__((address_space(1))) void*)g,
      (__attribute__((address_space(3))) void*)l, 16, 0, 0);
}

// ---------------------------------------------------------------------------
// wsplit: pack W into B-fragment order, 3 exact bf16 planes; zero ce/ssum.
// byte addr = c*24576 + ks*12288 + half*6144 + f2*3072 + plane*1024 + lane*16
// Fragment (c,ks,half,f2,plane,lane): e = half*32+f2*16+(lane&15),
//                                     k = c*64+ks*32+(lane>>4)*8
// ---------------------------------------------------------------------------
__global__ __launch_bounds__(256) void wsplit(const float* __restrict__ w,
                                              char* __restrict__ wpk,
                                              float* __restrict__ stats) {
  if (blockIdx.x == 0 && threadIdx.x < 128) {   // zero ce+ssum (512 floats)
    *(float4*)(stats + threadIdx.x * 4) = make_float4(0.f, 0.f, 0.f, 0.f);
  }
  int t = blockIdx.x * 256 + threadIdx.x;    // 16384 threads
  int lane = t & 63;
  int f2 = (t >> 6) & 1, half = (t >> 7) & 1, ks = (t >> 8) & 1, c = t >> 9;
  int e = half * 32 + f2 * 16 + (lane & 15);
  int k = c * 64 + ks * 32 + ((lane >> 4) << 3);
  const float* p = w + (size_t)e * HDIM + k;
  bf16x8 h8, m8, l8;
  split8(*(const float4*)p, *(const float4*)(p + 4), h8, m8, l8);
  union { bf16x8 v; uint4 u; } H, M, L;
  H.v = h8; M.v = m8; L.v = l8;
  size_t base = (size_t)c * 24576 + (size_t)ks * 12288 + (size_t)half * 6144
              + (size_t)f2 * 3072 + (size_t)lane * 16;
  *(uint4*)(wpk + base) = H.u;
  *(uint4*)(wpk + base + 1024) = M.u;
  *(uint4*)(wpk + base + 2048) = L.u;
}

// ---------------------------------------------------------------------------
// Fused gate. 512 blocks x 256 thr (4 waves), 2 blocks/CU.
// Wave = 16 tokens x 32 experts (2 C-frags).
// KEY CHANGE (r8 post-mortem): the K-loop contains NO register global loads.
// X is staged through LDS via global_load_lds with per-lane fragment-swizzled
// SOURCE addresses (m173 pattern) -> the compiler has no VMEM of its own to
// guard, so it inserts no vmcnt in the loop; the only VMEM wait is OUR single
// s_waitcnt vmcnt(0) per chunk (T3 2-phase: stage(c+1) at top, drain at
// bottom after a full chunk of compute).
// LDS: W dbuf 2x24KB @0, X dbuf 2x8KB @49152. 64KB total -> 2 blocks/CU.
// X slot s (0..511) = [tg(1b)][ks(1b)][q(1b)][lane(6b)] holds
//   x[token = t0+tg*16+(lane&15)][k = c*64+ks*32+(lane>>4)*8+q*4 ..+3]
// -> readback: lane reads its own slot at lane*16: conflict-free b128.
// ---------------------------------------------------------------------------
__global__ __launch_bounds__(256, 2) void gate_fused(const float* __restrict__ x,
                                                     const char* __restrict__ wpk,
                                                     float* __restrict__ out,
                                                     float* __restrict__ ce,
                                                     float* __restrict__ ssum) {
  __shared__ __align__(16) char lds[65536];   // [W0|W1|X0|X1]
  __shared__ float hist[NE];

  const int tid = threadIdx.x;
  const int bid = blockIdx.x;
  const int t0 = bid * BT;
  const int b = bid >> 7;                     // 128 blocks per batch row
  const int lane = tid & 63;
  const int wid = tid >> 6;                   // 0..3
  const int half = wid & 1;                   // expert half
  const int tg = (wid >> 1);                  // token group: 0 or 1

  if (tid < NE) hist[tid] = 0.f;

  // X staging: 2 slots per thread, s = r*256 + tid. Source is per-lane
  // (fragment-swizzled); dest base is wave-uniform (s>>6 constant per wave).
  const char* xsg[2];
  int xdo_[2];
#pragma unroll
  for (int r = 0; r < 2; ++r) {
    int s = r * 256 + tid;
    int stg = s >> 8, sks = (s >> 7) & 1, sq = (s >> 6) & 1, ln = s & 63;
    xsg[r] = (const char*)(x + (size_t)(t0 + stg * 16 + (ln & 15)) * HDIM
                           + sks * 32 + ((ln >> 4) << 3) + sq * 4);
    xdo_[r] = (r * 256 + wid * 64) * 16;      // wave-uniform dest offset
  }
  const char* wsrc = wpk + (size_t)lane * 16;

  f32x4 acc[2] = {{0.f, 0.f, 0.f, 0.f}, {0.f, 0.f, 0.f, 0.f}};

#define STAGE(cc, sel)                                                        \
  {                                                                           \
    char* wdst = lds + (sel) * 24576;                                         \
    const char* wp_ = wsrc + (size_t)(cc) * 24576;                            \
    _Pragma("unroll")                                                         \
    for (int i = 0; i < 6; ++i)                                               \
      gl_lds16(wp_ + (i * 4 + wid) * 1024, wdst + (i * 4 + wid) * 1024);      \
    char* xdst = lds + 49152 + (sel) * 8192;                                  \
    _Pragma("unroll")                                                         \
    for (int r = 0; r < 2; ++r)                                               \
      gl_lds16(xsg[r] + (size_t)(cc) * 256, xdst + xdo_[r]);                  \
  }

  // ---- prologue: stage chunk 0, drain, barrier
  STAGE(0, 0);
  asm volatile("s_waitcnt vmcnt(0)" ::: "memory");
  __builtin_amdgcn_s_barrier();
  asm volatile("" ::: "memory");

#pragma unroll 1
  for (int c = 0; c < NC; ++c) {
    const int sel = c & 1;
    if (c + 1 < NC) STAGE(c + 1, sel ^ 1);    // 1: stage next chunk (async)

    char* wb = lds + sel * 24576;
    char* xb = lds + 49152 + sel * 8192 + tg * 4096;
#pragma unroll
    for (int ks = 0; ks < 2; ++ks) {          // 2: X from LDS, split, MFMA
      float4 X0 = *(const float4*)(xb + ks * 2048 + lane * 16);
      float4 X1 = *(const float4*)(xb + ks * 2048 + 1024 + lane * 16);
      bf16x8 ah, am, al;
      split8(X0, X1, ah, am, al);
      const char* wk = wb + ks * 12288 + half * 6144 + lane * 16;
#pragma unroll
      for (int f2 = 0; f2 < 2; ++f2) {
        const char* bb = wk + f2 * 3072;
        bf16x8 bh = *(const bf16x8*)(bb);
        bf16x8 bm = *(const bf16x8*)(bb + 1024);
        bf16x8 bl = *(const bf16x8*)(bb + 2048);
        acc[f2] = __builtin_amdgcn_mfma_f32_16x16x32_bf16(ah, bh, acc[f2], 0, 0, 0);
        acc[f2] = __builtin_amdgcn_mfma_f32_16x16x32_bf16(ah, bm, acc[f2], 0, 0, 0);
        acc[f2] = __builtin_amdgcn_mfma_f32_16x16x32_bf16(am, bh, acc[f2], 0, 0, 0);
        acc[f2] = __builtin_amdgcn_mfma_f32_16x16x32_bf16(ah, bl, acc[f2], 0, 0, 0);
        acc[f2] = __builtin_amdgcn_mfma_f32_16x16x32_bf16(al, bh, acc[f2], 0, 0, 0);
        acc[f2] = __builtin_amdgcn_mfma_f32_16x16x32_bf16(am, bm, acc[f2], 0, 0, 0);
      }
    }
    // 3: drain the staging issued at top of THIS chunk (full chunk in flight)
    asm volatile("s_waitcnt vmcnt(0)" ::: "memory");
    __builtin_amdgcn_s_barrier();
    asm volatile("" ::: "memory");
  }
#undef STAGE

  // C frags -> sc[expert][token]. C layout: col(=expert)=lane&15,
  // row(=token)=(lane>>4)*4+reg  [m89-verified]
  float (*sc)[BT + 1] = (float(*)[BT + 1])lds;
#pragma unroll
  for (int f2 = 0; f2 < 2; ++f2) {
    int e = half * 32 + f2 * 16 + (lane & 15);
    int tk = tg * 16 + ((lane >> 4) << 2);
    sc[e][tk + 0] = acc[f2][0];
    sc[e][tk + 1] = acc[f2][1];
    sc[e][tk + 2] = acc[f2][2];
    sc[e][tk + 3] = acc[f2][3];
  }
  __syncthreads();

  // softmax + top-8: 8 lanes per token (t = 0..31), 8 experts per lane
  const int t = tid >> 3;
  const int j = tid & 7;
  float p[8];
#pragma unroll
  for (int i = 0; i < 8; ++i) p[i] = sc[j * 8 + i][t];

  float m = p[0];
#pragma unroll
  for (int i = 1; i < 8; ++i) m = fmaxf(m, p[i]);
  m = fmaxf(m, __shfl_xor(m, 1, 8));
  m = fmaxf(m, __shfl_xor(m, 2, 8));
  m = fmaxf(m, __shfl_xor(m, 4, 8));
  float s = 0.f;
#pragma unroll
  for (int i = 0; i < 8; ++i) { p[i] = __expf(p[i] - m); s += p[i]; }
  s += __shfl_xor(s, 1, 8);
  s += __shfl_xor(s, 2, 8);
  s += __shfl_xor(s, 4, 8);
  float inv = 1.f / s;
#pragma unroll
  for (int i = 0; i < 8; ++i) { p[i] *= inv; sc[j * 8 + i][t] = p[i]; }

  // top-8: strict-> scan (lowest idx on tie), 8-lane (val,idx) reduce
  unsigned used = 0;
  float wsum = 0.f;
  float wv[KTOP];
  int wi_[KTOP];
#pragma unroll
  for (int sel = 0; sel < KTOP; ++sel) {
    float bv = -1.f;
    int bi = 0;
#pragma unroll
    for (int i = 0; i < 8; ++i) {
      bool ok = !((used >> i) & 1u);
      if (ok && p[i] > bv) { bv = p[i]; bi = i; }
    }
    int ge = j * 8 + bi;
#pragma unroll
    for (int mk = 1; mk < 8; mk <<= 1) {
      float ov = __shfl_xor(bv, mk, 8);
      int og = __shfl_xor(ge, mk, 8);
      if (ov > bv || (ov == bv && og < ge)) { bv = ov; ge = og; }
    }
    if ((ge >> 3) == j) used |= 1u << (ge & 7);
    wv[sel] = bv;
    wi_[sel] = ge;
    wsum += bv;
  }
  if (j == 0) {
    float winv = 1.f / (wsum + 1e-20f);
#pragma unroll
    for (int sel = 0; sel < KTOP; ++sel) {
      out[(size_t)(t0 + t) * KTOP + sel] = (float)wi_[sel];
      out[(size_t)TOK * KTOP + (size_t)(t0 + t) * KTOP + sel] = wv[sel] * winv;
      atomicAdd(&hist[wi_[sel]], 1.f);
    }
  }
  __syncthreads();

  if (tid < NE) {
    float ssl = 0.f;
#pragma unroll
    for (int tt = 0; tt < BT; ++tt) ssl += sc[tid][tt];
    atomicAdd(&ssum[b * NE + tid], ssl);
    atomicAdd(&ce[b * NE + tid], hist[tid]);
  }
}

// ---------------------------------------------------------------------------
// Finalize expert_loads + aux_loss
// ---------------------------------------------------------------------------
__global__ __launch_bounds__(64) void gate_final(const float* __restrict__ ce,
                                                 const float* __restrict__ ssum,
                                                 float* __restrict__ out) {
  const int e = threadIdx.x;
  float loads = 0.f, aux = 0.f;
#pragma unroll
  for (int b = 0; b < NB; ++b) {
    float c = ce[b * 64 + e];
    loads += c;
    aux += (c / 512.0f) * (ssum[b * 64 + e] / 4096.0f);  // (S*K/E)=512, S=4096
  }
  out[(size_t)2 * TOK * KTOP + 1 + e] = loads;
#pragma unroll
  for (int off = 32; off > 0; off >>= 1) aux += __shfl_down(aux, off);
  if (e == 0) out[(size_t)2 * TOK * KTOP] = aux * (0.1f / 4.0f);  // ALPHA/B
}

extern "C" void kernel_launch(void* const* d_in, const int* in_sizes, int n_in,
                              void* d_out, int out_size, void* d_ws, size_t ws_size,
                              hipStream_t stream) {
  const float* x = (const float*)d_in[0];
  const float* w = (const float*)d_in[1];
  float* out = (float*)d_out;

  char* wpk = (char*)d_ws;                         // 32 chunks x 24 KB = 768 KB
  float* ce = (float*)(wpk + (size_t)NC * 24576);  // [NB][NE]
  float* ssum = ce + NB * NE;                      // [NB][NE]

  wsplit<<<dim3(64), dim3(256), 0, stream>>>(w, wpk, ce);
  gate_fused<<<dim3(TOK / BT), dim3(256), 0, stream>>>(x, wpk, out, ce, ssum);
  gate_final<<<dim3(1), dim3(64), 0, stream>>>(ce, ssum, out);
}